// Round 5
// baseline (302.797 us; speedup 1.0000x reference)
//
#include <hip/hip_runtime.h>

#define BDIM 4
#define LDIM 4096
#define DDIM 1024
#define KTAPS 128
#define LCHUNK 64

typedef __attribute__((ext_vector_type(8))) _Float16 f16x8;
typedef __attribute__((ext_vector_type(4))) float f32x4;

// ---------------------------------------------------------------------------
// fp16 helpers
// ---------------------------------------------------------------------------
__device__ __forceinline__ float f16_to_f(ushort h) {
    return (float)__builtin_bit_cast(_Float16, h);
}
__device__ __forceinline__ ushort f_to_f16(float f) {
    return __builtin_bit_cast(ushort, (_Float16)f);  // v_cvt_f16_f32, RNE
}

__device__ __forceinline__ void load_lds16(const ushort* g, ushort* l) {
    __builtin_amdgcn_global_load_lds(
        (const __attribute__((address_space(1))) void*)g,
        (__attribute__((address_space(3))) void*)l, 16, 0, 0);
}

// ---------------------------------------------------------------------------
// fp32 -> fp16 convert (vectorized, grid-stride)
// ---------------------------------------------------------------------------
__global__ __launch_bounds__(256) void to_f16(const float* __restrict__ in,
                                              ushort* __restrict__ out, int n4) {
    for (int i = blockIdx.x * 256 + threadIdx.x; i < n4; i += gridDim.x * 256) {
        const float4 v = *(const float4*)&in[(size_t)i * 4];
        ushort4 h;
        h.x = f_to_f16(v.x);
        h.y = f_to_f16(v.y);
        h.z = f_to_f16(v.z);
        h.w = f_to_f16(v.w);
        *(ushort4*)&out[(size_t)i * 4] = h;
    }
}

// ---------------------------------------------------------------------------
// 256x256 8-phase f16 NT GEMM (m201-style): BK=64, 8 waves (2Mx4N), dbuf LDS,
// K-half half-tiles, counted vmcnt(4) once per K-tile, setprio around MFMA.
// LDS granule layout per K-tile buffer: gran[(kh*4+kg)*256 + row] (16B each)
//   -> ds_read_b128 per 16-lane group = 16 consecutive granules (2-way, free)
//   -> global_load_lds linear in tid; per-lane global src supplies the layout.
// A [M,K] f16 row-major, B [N,K] f16 row-major. OBF=1 -> f16 C, else f32 C.
// ---------------------------------------------------------------------------
template <int OBF>
__global__ __launch_bounds__(512) void gemm256(const ushort* __restrict__ A,
                                               const ushort* __restrict__ B,
                                               void* __restrict__ Cp, int ldc, int K) {
    __shared__ ushort lds[65536];  // 128 KiB: [buf][mat][2048 granules][8]

    const int tid = threadIdx.x;
    const int lane = tid & 63;
    const int w = tid >> 6;
    const int wr = w >> 2;   // M-half (0..1)
    const int wc = w & 3;    // N-quarter (0..3)
    const int r16 = lane & 15;
    const int kgl = lane >> 4;  // k-granule of the MFMA operand (0..3)
    const int NT = K >> 6;      // K-tiles of 64

    // bijective XCD swizzle (nwg % 8 == 0 for our grids)
    const int gx = gridDim.x;
    const int nwg = gx * gridDim.y;
    const int orig = blockIdx.y * gx + blockIdx.x;
    const int q8 = nwg >> 3;
    const int tile = (orig & 7) * q8 + (orig >> 3);
    const int m0 = (tile / gx) * 256;
    const int n0 = (tile % gx) * 256;

    // staging: thread t covers granules t (kg=t>>8) and t+512 (kg+2), row mm=t&255
    const int mm = tid & 255;
    const int kg0 = tid >> 8;
    const ushort* pA0 = A + (size_t)(m0 + mm) * K + kg0 * 8;
    const ushort* pB0 = B + (size_t)(n0 + mm) * K + kg0 * 8;

    f32x4 acc[8][4] = {};

    auto STAGE = [&](const int mat, const int kt, const int kh, const int buf) {
        const ushort* s0 = (mat ? pB0 : pA0) + kt * 64 + kh * 32;
        ushort* l = lds + ((buf * 2 + mat) * 2048 + kh * 1024) * 8;
        load_lds16(s0, l + tid * 8);
        load_lds16(s0 + 16, l + (tid + 512) * 8);
    };

    // phase: 8 ds_read_b128 + optional half-tile stage + barrier + 16 MFMA
    // vm: -1 none, 0 -> vmcnt(0), 4 -> vmcnt(4)  (placed BEFORE final barrier
    // so the barrier makes the per-wave drain collective)
    auto PHASE = [&](const int buf, const int kh, const int ih, const int smat,
                     const int skt, const int skh, const int sbuf, const int vm) {
        const ushort* ab =
            lds + ((buf * 2 + 0) * 2048 + kh * 1024 + kgl * 256 + wr * 128 + ih * 64 + r16) * 8;
        const ushort* bb =
            lds + ((buf * 2 + 1) * 2048 + kh * 1024 + kgl * 256 + wc * 64 + r16) * 8;
        f16x8 a0 = *(const f16x8*)(ab);
        f16x8 a1 = *(const f16x8*)(ab + 128);
        f16x8 a2 = *(const f16x8*)(ab + 256);
        f16x8 a3 = *(const f16x8*)(ab + 384);
        f16x8 b0 = *(const f16x8*)(bb);
        f16x8 b1 = *(const f16x8*)(bb + 128);
        f16x8 b2 = *(const f16x8*)(bb + 256);
        f16x8 b3 = *(const f16x8*)(bb + 384);
        if (skt < NT) STAGE(smat, skt, skh, sbuf);
        __builtin_amdgcn_s_barrier();
        asm volatile("s_waitcnt lgkmcnt(0)" ::: "memory");
        __builtin_amdgcn_sched_barrier(0);
        __builtin_amdgcn_s_setprio(1);
        f32x4(*ap)[4] = acc + ih * 4;
        ap[0][0] = __builtin_amdgcn_mfma_f32_16x16x32_f16(a0, b0, ap[0][0], 0, 0, 0);
        ap[0][1] = __builtin_amdgcn_mfma_f32_16x16x32_f16(a0, b1, ap[0][1], 0, 0, 0);
        ap[0][2] = __builtin_amdgcn_mfma_f32_16x16x32_f16(a0, b2, ap[0][2], 0, 0, 0);
        ap[0][3] = __builtin_amdgcn_mfma_f32_16x16x32_f16(a0, b3, ap[0][3], 0, 0, 0);
        ap[1][0] = __builtin_amdgcn_mfma_f32_16x16x32_f16(a1, b0, ap[1][0], 0, 0, 0);
        ap[1][1] = __builtin_amdgcn_mfma_f32_16x16x32_f16(a1, b1, ap[1][1], 0, 0, 0);
        ap[1][2] = __builtin_amdgcn_mfma_f32_16x16x32_f16(a1, b2, ap[1][2], 0, 0, 0);
        ap[1][3] = __builtin_amdgcn_mfma_f32_16x16x32_f16(a1, b3, ap[1][3], 0, 0, 0);
        ap[2][0] = __builtin_amdgcn_mfma_f32_16x16x32_f16(a2, b0, ap[2][0], 0, 0, 0);
        ap[2][1] = __builtin_amdgcn_mfma_f32_16x16x32_f16(a2, b1, ap[2][1], 0, 0, 0);
        ap[2][2] = __builtin_amdgcn_mfma_f32_16x16x32_f16(a2, b2, ap[2][2], 0, 0, 0);
        ap[2][3] = __builtin_amdgcn_mfma_f32_16x16x32_f16(a2, b3, ap[2][3], 0, 0, 0);
        ap[3][0] = __builtin_amdgcn_mfma_f32_16x16x32_f16(a3, b0, ap[3][0], 0, 0, 0);
        ap[3][1] = __builtin_amdgcn_mfma_f32_16x16x32_f16(a3, b1, ap[3][1], 0, 0, 0);
        ap[3][2] = __builtin_amdgcn_mfma_f32_16x16x32_f16(a3, b2, ap[3][2], 0, 0, 0);
        ap[3][3] = __builtin_amdgcn_mfma_f32_16x16x32_f16(a3, b3, ap[3][3], 0, 0, 0);
        __builtin_amdgcn_s_setprio(0);
        if (vm == 0) {
            asm volatile("s_waitcnt vmcnt(0)" ::: "memory");
        } else if (vm > 0) {
            asm volatile("s_waitcnt vmcnt(4)" ::: "memory");
        }
        __builtin_amdgcn_s_barrier();
    };

    // prologue: tile0 (all 4 halves) + tile1 k-half0 -> vmcnt(4) leaves tile1's
    // A/B kh0 in flight, matching steady state.
    STAGE(0, 0, 0, 0);
    STAGE(1, 0, 0, 0);
    STAGE(0, 0, 1, 0);
    STAGE(1, 0, 1, 0);
    if (NT > 1) {
        STAGE(0, 1, 0, 1);
        STAGE(1, 1, 0, 1);
    }
    asm volatile("s_waitcnt vmcnt(4)" ::: "memory");
    __builtin_amdgcn_s_barrier();

    // steady state: group g computes K-tile g from buf g&1.
    // slots: p0 A(g+1,kh1)->nbuf  p1 B(g+1,kh1)->nbuf  p2 A(g+2,kh0)->buf
    //        p3 B(g+2,kh0)->buf, then vmcnt(4) (0 entering the last tile).
    for (int g = 0; g < NT; ++g) {
        const int buf = g & 1;
        const int nbuf = buf ^ 1;
        PHASE(buf, 0, 0, 0, g + 1, 1, nbuf, -1);
        PHASE(buf, 0, 1, 1, g + 1, 1, nbuf, -1);
        PHASE(buf, 1, 0, 0, g + 2, 0, buf, -1);
        PHASE(buf, 1, 1, 1, g + 2, 0, buf,
              (g == NT - 2) ? 0 : ((g == NT - 1) ? -1 : 4));
    }

    // epilogue: C/D layout (m89): col=lane&15 (n-side), row=(lane>>4)*4+q (m-side)
#pragma unroll
    for (int i = 0; i < 8; ++i) {
        const int row = m0 + wr * 128 + i * 16 + kgl * 4;
#pragma unroll
        for (int j = 0; j < 4; ++j) {
            const int col = n0 + wc * 64 + j * 16 + r16;
#pragma unroll
            for (int q = 0; q < 4; ++q) {
                if (OBF) {
                    ((ushort*)Cp)[(size_t)(row + q) * ldc + col] = f_to_f16(acc[i][j][q]);
                } else {
                    ((float*)Cp)[(size_t)(row + q) * ldc + col] = acc[i][j][q];
                }
            }
        }
    }
}

// ---------------------------------------------------------------------------
// conv + gate on fp16 qkv [B,L,3072]; writes gated fp16 [B,L,1024].
// decay geometric => exact IIR for the 128-tap FIR:
//   res[l] = r*res[l-1] + src[l] - decay128*src[l-128],  src = k*v (fp32 state)
// ---------------------------------------------------------------------------
__global__ __launch_bounds__(256) void conv_gate_f16(const ushort* __restrict__ qkvh,
                                                     const float* __restrict__ decay,
                                                     ushort* __restrict__ gh) {
    __shared__ float sdec[KTAPS];
    if (threadIdx.x < KTAPS) sdec[threadIdx.x] = decay[threadIdx.x];
    __syncthreads();

    const int d = blockIdx.y * 256 + threadIdx.x;
    const int b = blockIdx.z;
    const int l0 = blockIdx.x * LCHUNK;

    const float r = sdec[1];
    const float dlast = r * sdec[KTAPS - 1];  // decay[128]
    const size_t rs = 3 * DDIM;

    const ushort* base = qkvh + (size_t)b * LDIM * rs;
    const ushort* qc = base + d;
    const ushort* kc = base + DDIM + d;
    const ushort* vc = base + 2 * DDIM + d;
    ushort* g0 = gh + (size_t)b * LDIM * DDIM + d;

    float res = 0.f;
    int lstart;
    if (l0 == 0) {
        lstart = 0;
    } else {
        const int tmax = (l0 < KTAPS - 1) ? l0 : (KTAPS - 1);
#pragma unroll 4
        for (int t = 0; t <= tmax; ++t) {
            const size_t off = (size_t)(l0 - t) * rs;
            res += sdec[t] * f16_to_f(kc[off]) * f16_to_f(vc[off]);
        }
        g0[(size_t)l0 * DDIM] = f_to_f16(f16_to_f(qc[(size_t)l0 * rs]) * res);
        lstart = l0 + 1;
    }

    for (int l = lstart; l < l0 + LCHUNK; ++l) {
        const size_t off = (size_t)l * rs;
        const float s = f16_to_f(kc[off]) * f16_to_f(vc[off]);
        if (l == 0) {
            res = sdec[0] * s;
        } else {
            float sub = 0.f;
            if (l >= KTAPS) {
                const size_t o2 = (size_t)(l - KTAPS) * rs;
                sub = dlast * f16_to_f(kc[o2]) * f16_to_f(vc[o2]);
            }
            res = r * res + s - sub;
        }
        g0[(size_t)l * DDIM] = f_to_f16(f16_to_f(qc[off]) * res);
    }
}

// ---------------------------------------------------------------------------
// Memory plan (ws proven >= 192MB; uses 168MB):
//   ws[  0.. 96MB) qkvh  f16 [16384,3072]  GEMM1 out
//   ws[ 96..128MB) gh    f16 [16384,1024]  conv out = GEMM2 A
//   ws[128..160MB) xh    f16 [16384,1024]  GEMM1 A
//   ws[160..166MB) wqkvh f16 [3072,1024]   GEMM1 B
//   ws[166..168MB) wouth f16 [1024,1024]   GEMM2 B
// ---------------------------------------------------------------------------
extern "C" void kernel_launch(void* const* d_in, const int* in_sizes, int n_in,
                              void* d_out, int out_size, void* d_ws, size_t ws_size,
                              hipStream_t stream) {
    const float* x = (const float*)d_in[0];
    const float* Wqkv = (const float*)d_in[1];
    const float* Wout = (const float*)d_in[2];
    const float* decay = (const float*)d_in[3];

    const int M = BDIM * LDIM;  // 16384
    const size_t MB = 1024 * 1024;

    ushort* qkvh = (ushort*)d_ws;
    ushort* gh = (ushort*)((char*)d_ws + 96 * MB);
    ushort* xh = (ushort*)((char*)d_ws + 128 * MB);
    ushort* wqkvh = (ushort*)((char*)d_ws + 160 * MB);
    ushort* wouth = (ushort*)((char*)d_ws + 166 * MB);

    // converts
    to_f16<<<2048, 256, 0, stream>>>(x, xh, M * DDIM / 4);
    to_f16<<<1024, 256, 0, stream>>>(Wqkv, wqkvh, 3 * DDIM * DDIM / 4);
    to_f16<<<512, 256, 0, stream>>>(Wout, wouth, DDIM * DDIM / 4);

    // GEMM1: qkvh = xh @ wqkvh^T  [16384,1024]x[3072,1024]^T, f16 out
    dim3 g1(3 * DDIM / 256, M / 256);  // 12 x 64 = 768 wgs (%8==0)
    gemm256<1><<<g1, 512, 0, stream>>>(xh, wqkvh, qkvh, 3 * DDIM, DDIM);

    // conv + gate -> gh
    dim3 g2(LDIM / LCHUNK, DDIM / 256, BDIM);  // 64 x 4 x 4 = 1024 blocks
    conv_gate_f16<<<g2, 256, 0, stream>>>(qkvh, decay, gh);

    // GEMM2: out = gh @ wouth^T  [16384,1024]x[1024,1024]^T, f32 out
    dim3 g3(DDIM / 256, M / 256);  // 4 x 64 = 256 wgs (%8==0)
    gemm256<0><<<g3, 512, 0, stream>>>(gh, wouth, d_out, DDIM, DDIM);
}